// Round 18
// baseline (50.916 us; speedup 1.0000x reference)
//
#include <hip/hip_runtime.h>
#include <hip/hip_bf16.h>

// LoRA conv experts, algebraically collapsed into ONE rank-64 separable pair:
//   W1[(e,r)][kx*256+c] = p_e * w_in[e,r,c,0,kx]    (64 x 768)
//   W2[o][ky*64+(e,r)]  = w_out[e,o,r,ky,0]         (256 x 192)
// R18 = R13's layout/swizzles at stripe S=4 with 512-thread blocks:
//   256 blocks (16 b x 16 stripes) x 8 waves = 8 waves/CU (same as R13's
//   2 blocks x 4 waves), LDS 85KB -> 1 block/CU. Per output row: staging
//   1.5 x-rows (vs 2.0) and -17% MFMA. h-phase waves = 4 m-tiles x 2
//   n-halves; out-phase waves = 8 o-groups of 32. All index/swizzle forms
//   are R13's verbatim (quad key for xs, (n&7) key for hs, strides = 4 mod
//   32 dwords). Plain launch_bounds (no min-wave forcing — R5/7/9/14 lesson).

typedef __bf16 bf16x8 __attribute__((ext_vector_type(8)));
typedef __bf16 bf16x4 __attribute__((ext_vector_type(4)));
typedef float  f32x4  __attribute__((ext_vector_type(4)));

#define CIN_  256
#define COUT_ 256
#define M1    64
#define K1    768
#define K2    192
#define CS    264     // xs row stride (shorts) — R4-proven class (132 dw = 4 mod 32)
#define HSS   392     // hs row stride (shorts): 6*64 + 8 pad (196 dw = 4 mod 32)

static __device__ __forceinline__ unsigned short f2bf(float f) {
    union { float f; unsigned u; } v; v.f = f;
    unsigned r = v.u + 0x7FFFu + ((v.u >> 16) & 1u);
    return (unsigned short)(r >> 16);
}

// ------------- prep: fold probs, reorder, cast to bf16 (W1, W2) -------------
__global__ void prep_weights(const float* __restrict__ probs,
                             const float* __restrict__ w_in,
                             const float* __restrict__ w_out,
                             unsigned short* __restrict__ W1,
                             unsigned short* __restrict__ W2) {
    int idx = blockIdx.x * blockDim.x + threadIdx.x;
    if (idx < M1 * K1) {
        int er = idx / K1, rem = idx % K1;
        int kx = rem / CIN_, c = rem % CIN_;
        int e = er >> 3;
        W1[idx] = f2bf(probs[e] * w_in[(er * CIN_ + c) * 3 + kx]);
    } else {
        int i2 = idx - M1 * K1;   // grid sized exactly: i2 < COUT_*K2
        int o = i2 / K2, rem = i2 % K2;
        int ky = rem / M1, er = rem % M1;
        int e = er >> 3, r = er & 7;
        W2[i2] = f2bf(w_out[((e * COUT_ + o) * 8 + r) * 3 + ky]);
    }
}

// ----------------------------- fused conv kernel -----------------------------
// grid = 16 b * 16 stripes = 256 blocks, 512 threads (8 waves), 85KB LDS.
__global__ __launch_bounds__(512)
void fused_kernel(const float* __restrict__ x,
                  const unsigned short* __restrict__ W1,
                  const unsigned short* __restrict__ W2,
                  float* __restrict__ out) {
    __shared__ unsigned short xs[66 * CS];   // x row tile, transposed [ns][c^key]
    __shared__ unsigned short hs[64 * HSS];  // h tile [n][(yy*64+m)^((n&7)<<3)]
    const int bid  = blockIdx.x;
    // XCD swizzle decode: bid = (b%8) + 8*(s + 16*(b/8))  (bijective, 256 blocks)
    const int b    = (bid & 7) + ((bid >> 7) << 3);
    const int s    = (bid >> 3) & 15;
    const int y0   = s << 2;                 // stripe of 4 output rows
    const int tid  = threadIdx.x;
    const int lane = tid & 63;
    const int wave = tid >> 6;               // 0..7
    const int g    = lane >> 4;
    const int lr   = lane & 15;
    const int mt   = wave & 3;               // h-phase: m-tile
    const int nh   = wave >> 2;              // h-phase: n-half (0: n<32, 1: n>=32)

    // hoist W1 fragments for this wave's m-row (24 frags = 96 VGPR)
    bf16x8 w1f[3][8];
    {
        const unsigned short* w1p = W1 + (mt * 16 + lr) * K1 + g * 8;
        #pragma unroll
        for (int kx = 0; kx < 3; ++kx)
            #pragma unroll
            for (int cc = 0; cc < 8; ++cc)
                w1f[kx][cc] = *(const bf16x8*)(w1p + kx * CIN_ + cc * 32);
    }

    // zero xs halo rows ns=0 (n=-1) and ns=65 (n=64), once
    if (tid < 66) {
        int row = (tid < 33) ? 0 : 65;
        int col = (tid - (tid < 33 ? 0 : 33)) * 8;
        bf16x4 z4 = {};
        *(bf16x4*)&xs[row * CS + col] = z4;
        *(bf16x4*)&xs[row * CS + col + 4] = z4;
    }

    // staging map (R13 pattern at 512 thr): crow = tid>>4 (0..31),
    // n-quad n4 = (tid&15)*4, quad key swzt = ((n4>>2)&7)<<3 = (tid&7)<<3
    const int crow = tid >> 4;
    const int n4   = (tid & 15) << 2;
    const int swzt = (tid & 7) << 3;

    // ---------------- h-phase: 6 rows y = y0-1 .. y0+4 ----------------
    for (int yy = 0; yy < 6; ++yy) {
        const int y = y0 - 1 + yy;
        const bool yok = ((unsigned)y < 64u);
        __syncthreads();                      // xs free
        const float* xbase = x + ((b * CIN_ + crow) * 64 + (yok ? y : 0)) * 64 + n4;
        unsigned short* wr = &xs[(n4 + 1) * CS];
        #pragma unroll
        for (int r = 0; r < 2; ++r) {
            float4 ld[4];
            if (yok) {
                #pragma unroll
                for (int q = 0; q < 4; ++q)
                    ld[q] = *(const float4*)(xbase + (r * 4 + q) * 32 * 4096);
            } else {
                #pragma unroll
                for (int q = 0; q < 4; ++q) ld[q] = make_float4(0.f, 0.f, 0.f, 0.f);
            }
            #pragma unroll
            for (int q = 0; q < 4; ++q) {
                int cx = ((r * 4 + q) * 32 + crow) ^ swzt;
                *(__bf16*)&wr[0 * CS + cx] = (__bf16)ld[q].x;
                *(__bf16*)&wr[1 * CS + cx] = (__bf16)ld[q].y;
                *(__bf16*)&wr[2 * CS + cx] = (__bf16)ld[q].z;
                *(__bf16*)&wr[3 * CS + cx] = (__bf16)ld[q].w;
            }
        }
        __syncthreads();                      // xs ready

        f32x4 acc[2];
        acc[0] = (f32x4){0.f, 0.f, 0.f, 0.f};
        acc[1] = (f32x4){0.f, 0.f, 0.f, 0.f};
        #pragma unroll
        for (int kx = 0; kx < 3; ++kx) {
            int nA = nh * 32 + lr + kx - 1;           // logical n, nt=0
            int nB = nA + 16;                          // nt=1
            int szA = ((nA >> 2) & 7) << 3;
            int szB = ((nB >> 2) & 7) << 3;
            const unsigned short* rA = &xs[(nA + 1) * CS];
            const unsigned short* rB = &xs[(nB + 1) * CS];
            #pragma unroll
            for (int cc = 0; cc < 8; ++cc) {
                int co = cc * 32 + g * 8;
                acc[0] = __builtin_amdgcn_mfma_f32_16x16x32_bf16(
                    w1f[kx][cc], *(const bf16x8*)&rA[co ^ szA], acc[0], 0, 0, 0);
                acc[1] = __builtin_amdgcn_mfma_f32_16x16x32_bf16(
                    w1f[kx][cc], *(const bf16x8*)&rB[co ^ szB], acc[1], 0, 0, 0);
            }
        }
        // D: col=lr (n), row=g*4+r2 (m). b64 into hs, key (n&7).
        #pragma unroll
        for (int nt = 0; nt < 2; ++nt) {
            int n = nh * 32 + nt * 16 + lr;
            bf16x4 pk;
            #pragma unroll
            for (int r2 = 0; r2 < 4; ++r2) pk[r2] = (__bf16)acc[nt][r2];
            int col = (yy * 64 + mt * 16 + g * 4) ^ ((n & 7) << 3);
            *(bf16x4*)&hs[n * HSS + col] = pk;
        }
    }
    __syncthreads();                          // hs complete

    // ---------------- conv_out phase: 4 output rows ----------------
    // wave owns o in [wave*32, wave*32+32); w1f dead, registers reused.
    bf16x8 w2f[2][6];
    #pragma unroll
    for (int ot = 0; ot < 2; ++ot)
        #pragma unroll
        for (int kc = 0; kc < 6; ++kc)
            w2f[ot][kc] = *(const bf16x8*)(W2 + ((wave * 2 + ot) * 16 + lr) * K2 +
                                           kc * 32 + g * 8);

    #pragma unroll
    for (int ry = 0; ry < 4; ++ry) {
        f32x4 acc2[2][4];
        #pragma unroll
        for (int ot = 0; ot < 2; ++ot)
            #pragma unroll
            for (int nt = 0; nt < 4; ++nt) acc2[ot][nt] = (f32x4){0.f, 0.f, 0.f, 0.f};

        #pragma unroll
        for (int kc = 0; kc < 6; ++kc) {
            bf16x8 bfrag[4];
            #pragma unroll
            for (int nt = 0; nt < 4; ++nt) {
                int n = nt * 16 + lr;
                int col = (ry * 64 + kc * 32 + g * 8) ^ ((n & 7) << 3);
                bfrag[nt] = *(const bf16x8*)&hs[n * HSS + col];
            }
            #pragma unroll
            for (int ot = 0; ot < 2; ++ot)
                #pragma unroll
                for (int nt = 0; nt < 4; ++nt)
                    acc2[ot][nt] = __builtin_amdgcn_mfma_f32_16x16x32_bf16(
                        w2f[ot][kc], bfrag[nt], acc2[ot][nt], 0, 0, 0);
        }

        const int yo = y0 + ry;
        #pragma unroll
        for (int ot = 0; ot < 2; ++ot) {
            #pragma unroll
            for (int r2 = 0; r2 < 4; ++r2) {
                int o = (wave * 2 + ot) * 16 + g * 4 + r2;
                float* orow = out + ((b * COUT_ + o) * 64 + yo) * 64;
                #pragma unroll
                for (int nt = 0; nt < 4; ++nt)
                    orow[nt * 16 + lr] = acc2[ot][nt][r2];
            }
        }
    }
}

extern "C" void kernel_launch(void* const* d_in, const int* in_sizes, int n_in,
                              void* d_out, int out_size, void* d_ws, size_t ws_size,
                              hipStream_t stream) {
    const float* x     = (const float*)d_in[0];   // [16,256,64,64]
    const float* probs = (const float*)d_in[1];   // [8]
    const float* w_in  = (const float*)d_in[2];   // [8,8,256,1,3]
    const float* w_out = (const float*)d_in[3];   // [8,256,8,3,1]
    float* out = (float*)d_out;                   // [16,256,64,64] f32

    unsigned short* W1 = (unsigned short*)d_ws;   // 64*768 bf16
    unsigned short* W2 = W1 + M1 * K1;            // 256*192 bf16

    // 2*M1*K1 = 98304 = 384*256 exactly (M1*K1 == COUT_*K2)
    prep_weights<<<384, 256, 0, stream>>>(probs, w_in, w_out, W1, W2);
    fused_kernel<<<16 * 16, 512, 0, stream>>>(x, W1, W2, out);
}

// Round 19
// 47.764 us; speedup vs baseline: 1.0660x; 1.0660x over previous
//
#include <hip/hip_runtime.h>
#include <hip/hip_bf16.h>

// LoRA conv experts, algebraically collapsed into ONE rank-64 separable pair:
//   W1[(e,r)][kx*256+c] = p_e * w_in[e,r,c,0,kx]    (64 x 768)
//   W2[o][ky*64+(e,r)]  = w_out[e,o,r,ky,0]         (256 x 192)
// R19 = R13 restored verbatim — the session's best-measured kernel
// (47.9/47.8us total across two runs; fused steady 42.7-43.7us).
// R18 (S=4 stripe) proved the plateau: -25% HBM reads and -17% MFMA moved
// dur by ~0 — time is pinned by the serial phase structure (barrier ->
// exposed load latency -> MFMA chain), which every pipelining/occupancy
// remedy (R5-R10) made worse on this 2-blocks/CU, 67KB-LDS geometry.

typedef __bf16 bf16x8 __attribute__((ext_vector_type(8)));
typedef __bf16 bf16x4 __attribute__((ext_vector_type(4)));
typedef float  f32x4  __attribute__((ext_vector_type(4)));

#define CIN_  256
#define COUT_ 256
#define M1    64
#define K1    768
#define K2    192
#define CS    264     // xs row stride (shorts) — R4-proven
#define HS2   264     // hs row stride (shorts) — R4-proven

static __device__ __forceinline__ unsigned short f2bf(float f) {
    union { float f; unsigned u; } v; v.f = f;
    unsigned r = v.u + 0x7FFFu + ((v.u >> 16) & 1u);
    return (unsigned short)(r >> 16);
}

// ------------- prep: fold probs, reorder, cast to bf16 (W1, W2) -------------
__global__ void prep_weights(const float* __restrict__ probs,
                             const float* __restrict__ w_in,
                             const float* __restrict__ w_out,
                             unsigned short* __restrict__ W1,
                             unsigned short* __restrict__ W2) {
    int idx = blockIdx.x * blockDim.x + threadIdx.x;
    if (idx < M1 * K1) {
        int er = idx / K1, rem = idx % K1;
        int kx = rem / CIN_, c = rem % CIN_;
        int e = er >> 3;
        W1[idx] = f2bf(probs[e] * w_in[(er * CIN_ + c) * 3 + kx]);
    } else {
        int i2 = idx - M1 * K1;   // grid sized exactly: i2 < COUT_*K2
        int o = i2 / K2, rem = i2 % K2;
        int ky = rem / M1, er = rem % M1;
        int e = er >> 3, r = er & 7;
        W2[i2] = f2bf(w_out[((e * COUT_ + o) * 8 + r) * 3 + ky]);
    }
}

// ----------------------------- fused conv kernel -----------------------------
// grid = 16 b * 32 stripes = 512 blocks, 256 threads (4 waves), 67KB LDS.
__global__ __launch_bounds__(256, 2)
void fused_kernel(const float* __restrict__ x,
                  const unsigned short* __restrict__ W1,
                  const unsigned short* __restrict__ W2,
                  float* __restrict__ out) {
    __shared__ unsigned short xs[66 * CS];   // x row tile, transposed [ns][c]
    __shared__ unsigned short hs[64 * HS2];  // h tile [n][yy*64+m], XOR-swizzled
    const int bid  = blockIdx.x;
    // XCD swizzle decode: bid = (b%8) + 8*(s + 32*(b/8))
    const int b    = (bid & 7) + ((bid >> 8) << 3);
    const int s    = (bid >> 3) & 31;
    const int y0   = s << 1;
    const int tid  = threadIdx.x;
    const int lane = tid & 63;
    const int wave = tid >> 6;       // wave = m-tile for h-phase
    const int g    = lane >> 4;
    const int lr   = lane & 15;

    // hoist W1 fragments for this wave's m-row (24 frags = 96 VGPR)
    bf16x8 w1f[3][8];
    {
        const unsigned short* w1p = W1 + (wave * 16 + lr) * K1 + g * 8;
        #pragma unroll
        for (int kx = 0; kx < 3; ++kx)
            #pragma unroll
            for (int cc = 0; cc < 8; ++cc)
                w1f[kx][cc] = *(const bf16x8*)(w1p + kx * CIN_ + cc * 32);
    }

    // zero xs halo rows ns=0 (n=-1) and ns=65 (n=64), once
    if (tid < 66) {
        int row = (tid < 33) ? 0 : 65;
        int col = (tid - (tid < 33 ? 0 : 33)) * 8;
        bf16x4 z4 = {};
        *(bf16x4*)&xs[row * CS + col] = z4;
        *(bf16x4*)&xs[row * CS + col + 4] = z4;
    }

    // staging map (R4-proven): thread t -> c-row = t>>4, n-quad = (t&15)*4
    const int crow = tid >> 4;
    const int n4   = (tid & 15) << 2;
    const int swzt = (tid & 7) << 3;          // ((n4>>2)&7)<<3

    // ---------------- h-phase: 4 rows y = y0-1 .. y0+2 ----------------
    for (int yy = 0; yy < 4; ++yy) {
        const int y = y0 - 1 + yy;
        const bool yok = ((unsigned)y < 64u);
        __syncthreads();                      // xs free
        const float* xbase = x + ((b * CIN_ + crow) * 64 + (yok ? y : 0)) * 64 + n4;
        unsigned short* wr = &xs[(n4 + 1) * CS];
        #pragma unroll
        for (int r = 0; r < 4; ++r) {
            float4 ld[4];
            if (yok) {
                #pragma unroll
                for (int q = 0; q < 4; ++q)
                    ld[q] = *(const float4*)(xbase + (r * 4 + q) * 16 * 4096);
            } else {
                #pragma unroll
                for (int q = 0; q < 4; ++q) ld[q] = make_float4(0.f, 0.f, 0.f, 0.f);
            }
            #pragma unroll
            for (int q = 0; q < 4; ++q) {
                int cx = ((r * 4 + q) * 16 + crow) ^ swzt;
                *(__bf16*)&wr[0 * CS + cx] = (__bf16)ld[q].x;
                *(__bf16*)&wr[1 * CS + cx] = (__bf16)ld[q].y;
                *(__bf16*)&wr[2 * CS + cx] = (__bf16)ld[q].z;
                *(__bf16*)&wr[3 * CS + cx] = (__bf16)ld[q].w;
            }
        }
        __syncthreads();                      // xs ready

        f32x4 acc[4];
        #pragma unroll
        for (int i = 0; i < 4; ++i) acc[i] = (f32x4){0.f, 0.f, 0.f, 0.f};
        #pragma unroll
        for (int kx = 0; kx < 3; ++kx) {
            int ns0 = lr + kx;
            int sz0 = (((ns0 - 1) >> 2) & 7) << 3;
            int ns1 = ns0 + 16, sz1 = (((ns1 - 1) >> 2) & 7) << 3;
            int ns2 = ns0 + 32, sz2 = (((ns2 - 1) >> 2) & 7) << 3;
            int ns3 = ns0 + 48, sz3 = (((ns3 - 1) >> 2) & 7) << 3;
            const unsigned short* r0  = &xs[ns0 * CS];
            const unsigned short* r1  = &xs[ns1 * CS];
            const unsigned short* r2p = &xs[ns2 * CS];
            const unsigned short* r3  = &xs[ns3 * CS];
            #pragma unroll
            for (int cc = 0; cc < 8; ++cc) {
                int co = cc * 32 + g * 8;
                acc[0] = __builtin_amdgcn_mfma_f32_16x16x32_bf16(
                    w1f[kx][cc], *(const bf16x8*)&r0[co ^ sz0], acc[0], 0, 0, 0);
                acc[1] = __builtin_amdgcn_mfma_f32_16x16x32_bf16(
                    w1f[kx][cc], *(const bf16x8*)&r1[co ^ sz1], acc[1], 0, 0, 0);
                acc[2] = __builtin_amdgcn_mfma_f32_16x16x32_bf16(
                    w1f[kx][cc], *(const bf16x8*)&r2p[co ^ sz2], acc[2], 0, 0, 0);
                acc[3] = __builtin_amdgcn_mfma_f32_16x16x32_bf16(
                    w1f[kx][cc], *(const bf16x8*)&r3[co ^ sz3], acc[3], 0, 0, 0);
            }
        }
        // D: col=lr (n), row=g*4+r2 (m). Write h row into hs (swizzled cols).
        #pragma unroll
        for (int nt = 0; nt < 4; ++nt) {
            int n = nt * 16 + lr;
            bf16x4 pk;
            #pragma unroll
            for (int r2 = 0; r2 < 4; ++r2) pk[r2] = (__bf16)acc[nt][r2];
            int col = (yy * 64 + wave * 16 + g * 4) ^ ((n & 7) << 3);
            *(bf16x4*)&hs[n * HS2 + col] = pk;
        }
    }
    __syncthreads();                          // hs complete

    // ---------------- conv_out phase: 2 output rows ----------------
    bf16x8 w2f[4][6];                         // w1f dead; reuses its registers
    #pragma unroll
    for (int ot = 0; ot < 4; ++ot)
        #pragma unroll
        for (int kc = 0; kc < 6; ++kc)
            w2f[ot][kc] = *(const bf16x8*)(W2 + ((wave * 4 + ot) * 16 + lr) * K2 +
                                           kc * 32 + g * 8);

    #pragma unroll
    for (int ry = 0; ry < 2; ++ry) {
        f32x4 acc2[4][4];
        #pragma unroll
        for (int ot = 0; ot < 4; ++ot)
            #pragma unroll
            for (int nt = 0; nt < 4; ++nt) acc2[ot][nt] = (f32x4){0.f, 0.f, 0.f, 0.f};

        #pragma unroll
        for (int kc = 0; kc < 6; ++kc) {
            bf16x8 bfrag[4];
            #pragma unroll
            for (int nt = 0; nt < 4; ++nt) {
                int n = nt * 16 + lr;
                int col = (ry * 64 + kc * 32 + g * 8) ^ ((n & 7) << 3);
                bfrag[nt] = *(const bf16x8*)&hs[n * HS2 + col];
            }
            #pragma unroll
            for (int ot = 0; ot < 4; ++ot)
                #pragma unroll
                for (int nt = 0; nt < 4; ++nt)
                    acc2[ot][nt] = __builtin_amdgcn_mfma_f32_16x16x32_bf16(
                        w2f[ot][kc], bfrag[nt], acc2[ot][nt], 0, 0, 0);
        }

        const int yo = y0 + ry;
        #pragma unroll
        for (int ot = 0; ot < 4; ++ot) {
            #pragma unroll
            for (int r2 = 0; r2 < 4; ++r2) {
                int o = (wave * 4 + ot) * 16 + g * 4 + r2;
                float* orow = out + ((b * COUT_ + o) * 64 + yo) * 64;
                #pragma unroll
                for (int nt = 0; nt < 4; ++nt)
                    orow[nt * 16 + lr] = acc2[ot][nt][r2];
            }
        }
    }
}

extern "C" void kernel_launch(void* const* d_in, const int* in_sizes, int n_in,
                              void* d_out, int out_size, void* d_ws, size_t ws_size,
                              hipStream_t stream) {
    const float* x     = (const float*)d_in[0];   // [16,256,64,64]
    const float* probs = (const float*)d_in[1];   // [8]
    const float* w_in  = (const float*)d_in[2];   // [8,8,256,1,3]
    const float* w_out = (const float*)d_in[3];   // [8,256,8,3,1]
    float* out = (float*)d_out;                   // [16,256,64,64] f32

    unsigned short* W1 = (unsigned short*)d_ws;   // 64*768 bf16
    unsigned short* W2 = W1 + M1 * K1;            // 256*192 bf16

    // 2*M1*K1 = 98304 = 384*256 exactly (M1*K1 == COUT_*K2)
    prep_weights<<<384, 256, 0, stream>>>(probs, w_in, w_out, W1, W2);
    fused_kernel<<<16 * 32, 256, 0, stream>>>(x, W1, W2, out);
}